// Round 9
// baseline (2670.450 us; speedup 1.0000x reference)
//
#include <hip/hip_runtime.h>
#include <math.h>

#define NTRAJ 32
#define TLEN  64
#define BATCH (NTRAJ*TLEN)   // 2048

__device__ __forceinline__ float eluf(float x){ return x > 0.f ? x : expm1f(x); }
__device__ __forceinline__ float sigmf(float x){ return 1.f/(1.f+expf(-x)); }

// ---------------- conv1 (pair): NHWC C=4 -> NHWC [2048][42][42][32] -----------
// Contiguous fully-used reads (C=4 -> no channel-loop thrash mechanism).
__global__ __launch_bounds__(256) void conv1_kernel(
    const float* __restrict__ in,   // [2048][84][84][4]
    const float* __restrict__ w,    // [3][3][4][32] HWIO
    const float* __restrict__ b,    // [32]
    float* __restrict__ out)        // [2048][42][42][32]
{
    constexpr int IH=84, IW=84, OH=42, OW=42, PPR=21;   // 21 pairs/row
    int bid = blockIdx.x;
    bid = (bid & 7)*882 + (bid >> 3);            // XCD swizzle (7056/8)
    int pos = bid*256 + threadIdx.x;             // 1,806,336 exactly
    int n   = pos / (OH*PPR);
    int rem = pos % (OH*PPR);
    int oy  = rem / PPR;
    int ox0 = 2*(rem % PPR);                     // OW even -> pair always valid
    float acc0[32], acc1[32];
    #pragma unroll
    for(int o=0;o<32;o++){ acc0[o] = b[o]; acc1[o] = b[o]; }
    const int ix0 = 2*ox0;                       // PB = 0
    for(int ky=0; ky<3; ky++){
        int iy = 2*oy + ky;
        if(iy >= IH) continue;
        const float* rowp = in + ((size_t)(n*IH + iy)*IW)*4;
        float4 xc[5];
        #pragma unroll
        for(int j=0;j<5;j++){
            int ixc = ix0 + j;
            xc[j] = (ixc < IW) ? *(const float4*)(rowp + ixc*4)
                               : make_float4(0.f,0.f,0.f,0.f);
        }
        #pragma unroll
        for(int kx=0;kx<3;kx++){
            const float* wk = w + (ky*3 + kx)*128;
            const float* xa = (const float*)&xc[kx];
            const float* xb = (const float*)&xc[kx+2];
            #pragma unroll
            for(int e=0;e<4;e++){
                float a_ = xa[e], b_ = xb[e];
                const float* wo = wk + e*32;
                #pragma unroll
                for(int o=0;o<32;o++){ acc0[o] += a_*wo[o]; acc1[o] += b_*wo[o]; }
            }
        }
    }
    float4* op = (float4*)(out + ((size_t)(n*OH + oy)*OW + ox0)*32);
    #pragma unroll
    for(int q=0;q<8;q++)
        op[q] = make_float4(eluf(acc0[4*q]), eluf(acc0[4*q+1]),
                            eluf(acc0[4*q+2]), eluf(acc0[4*q+3]));
    #pragma unroll
    for(int q=0;q<8;q++)
        op[8+q] = make_float4(eluf(acc1[4*q]), eluf(acc1[4*q+1]),
                              eluf(acc1[4*q+2]), eluf(acc1[4*q+3]));
}

// ---------------- conv2/3/4 (LDS + wave-split channels) -----------------------
// WG = one row-tile of one image, ALL 32 input channels staged once (explicit
// reuse -> no cache thrash). wave = 8-output-channel group (weights stay
// wave-uniform -> s_load), lane = output pixel; acc[8]/thread.
// LDS 16-38 KB -> 4+ WG/CU. 2 barriers per WG total.
template<int IH,int IW,int OH,int OW,int PB,int OROWS,int NTILES,int PXR>
__global__ __launch_bounds__(256) void convS_kernel(
    const float* __restrict__ in,   // [BATCH][IH][IW][32]
    const float* __restrict__ w,    // [3][3][32][32] HWIO
    const float* __restrict__ b,    // [32]
    float* __restrict__ out)        // [BATCH][OH][OW][32]
{
    constexpr int SROWS = (NTILES==1) ? IH : (2*OROWS+1);
    constexpr int NPX   = SROWS*IW;
    constexpr int NPXP  = NPX | 1;                  // odd plane stride
    __shared__ float xs[32*NPXP];
    int bid = blockIdx.x;
    bid = (bid & 7)*(gridDim.x >> 3) + (bid >> 3);  // XCD swizzle (%8==0)
    const int img  = bid / NTILES;
    const int tile = bid % NTILES;
    const int oy0  = tile*OROWS;
    const int R    = (NTILES==1) ? OH : min(OROWS, OH-oy0);
    const int iy0  = (NTILES==1) ? 0 : (2*oy0 - PB);
    const int ys   = max(iy0, 0);
    const int rows = min(IH, iy0 + SROWS) - ys;
    const int t = threadIdx.x;
    // stage: contiguous f4 reads (each input byte fetched exactly once)
    const float4* gs = (const float4*)(in + ((size_t)img*IH + ys)*IW*32);
    for(int e = t; e < rows*IW*8; e += 256){
        int px = e >> 3, c4 = e & 7;
        float4 v = gs[e];
        xs[(c4*4+0)*NPXP + px] = v.x;
        xs[(c4*4+1)*NPXP + px] = v.y;
        xs[(c4*4+2)*NPXP + px] = v.z;
        xs[(c4*4+3)*NPXP + px] = v.w;
    }
    __syncthreads();
    const int og   = t >> 6;        // wave -> out-channel group (8 ch)
    const int lane = t & 63;
    #pragma unroll
    for(int r = 0; r < PXR; ++r){
        int p = lane + r*64;
        if(p < R*OW){
            int oy = oy0 + p/OW, ox = p%OW;
            float acc[8];
            #pragma unroll
            for(int o=0;o<8;o++) acc[o] = b[og*8+o];
            for(int ky=0;ky<3;ky++){
                int iy = 2*oy + ky - PB;
                if((unsigned)iy >= (unsigned)IH) continue;
                for(int kx=0;kx<3;kx++){
                    int ix = 2*ox + kx - PB;
                    if((unsigned)ix >= (unsigned)IW) continue;
                    int base = (iy - ys)*IW + ix;
                    const float* wt = w + (ky*3+kx)*1024 + og*8;  // uniform
                    #pragma unroll
                    for(int ci=0;ci<32;ci++){
                        float x = xs[ci*NPXP + base];
                        const float* wo = wt + ci*32;
                        #pragma unroll
                        for(int o=0;o<8;o++) acc[o] += x*wo[o];
                    }
                }
            }
            float4* op = (float4*)(out + ((size_t)(img*OH+oy)*OW+ox)*32 + og*8);
            op[0] = make_float4(eluf(acc[0]),eluf(acc[1]),eluf(acc[2]),eluf(acc[3]));
            op[1] = make_float4(eluf(acc[4]),eluf(acc[5]),eluf(acc[6]),eluf(acc[7]));
        }
    }
}

// ---------------- conv4 NHWC ([nt][feat]) -> A_T[feat=1152][row=2048] ---------
// Also zeroes the tagged h-exchange buffer every launch (poison/rep safe).
__global__ __launch_bounds__(256) void relayout_kernel(
    const float* __restrict__ p4,   // [2048(nt)][1152(f)]
    float* __restrict__ at,         // [1152][2048], row r = t*32+n
    unsigned long long* __restrict__ hbuf)  // [64][32][256] tagged
{
    int i = blockIdx.x*256 + threadIdx.x;   // 2,359,296 exactly
    if(i < 64*8192) hbuf[i] = 0ull;         // clear tags
    int f = i >> 11, r = i & 2047;          // write coalesced over r
    int tt = r >> 5, n = r & 31;            // r = t*32 + n
    int nt = n*64 + tt;
    at[i] = p4[nt*1152 + f];
}

// ---------------- gate pre-projection: gx[r][1024] = A_T^T @ Wx + b ----------
__global__ __launch_bounds__(256) void gx_gemm_kernel(
    const float* __restrict__ at,   // [1152][2048]
    const float* __restrict__ lw,   // [1408][1024] (rows 0..1151 = Wx)
    const float* __restrict__ lb,   // [1024]
    float* __restrict__ gx)         // [2048][1024], row r = t*32+n
{
    int lane = threadIdx.x & 63;
    int wv   = threadIdx.x >> 6;
    int r0   = blockIdx.x * 32;                    // grid.x = 64
    int oc   = blockIdx.y*256 + wv*64 + lane;      // grid.y = 4
    float acc[32];
    float bias = lb[oc];
    #pragma unroll
    for(int i=0;i<32;i++) acc[i] = bias;
    #pragma unroll 2
    for(int k=0;k<1152;k++){
        float wval = lw[k*1024 + oc];              // coalesced v-load
        const float* ap = at + k*2048 + r0;        // uniform -> s_load_dwordx16
        #pragma unroll
        for(int i=0;i<32;i++) acc[i] += ap[i] * wval;
    }
    #pragma unroll
    for(int i=0;i<32;i++) gx[(r0+i)*1024 + oc] = acc[i];  // coalesced
}

// ---------------- cooperative weight-stationary LSTM, 32 WGs ------------------
// (unchanged: batched tagged u64 exchange, fence-free)
__global__ __launch_bounds__(256) void lstm_coop_kernel(
    const float* __restrict__ gx,   // [2048][1024], row = st*32+n (bias folded)
    const float* __restrict__ lw,   // [1408][1024]; rows 1152.. = Wh
    const float* __restrict__ c0,   // [32][256]
    const float* __restrict__ h0,   // [32][256]
    float* __restrict__ feats,      // [2048][256], row = n*64+st
    unsigned long long* __restrict__ hbuf)  // [64][32][256] tagged, pre-zeroed
{
    __shared__ float hs[32*260];    // h(st-1), row stride 260 (bank-spread)
    __shared__ float wp[16*516];    // Wh pairs, stride 129 f4
    __shared__ float gl[32*33];     // gate buffer

    const int wg = blockIdx.x;      // 0..31
    const int t  = threadIdx.x;
    const float* wh = lw + 1152*1024;

    for(int i=0;i<32;i++){
        int e = t + 256*i;                  // 8192 elements
        int k = e >> 5, c = e & 31;
        int gc = (c>>3)*256 + wg*8 + (c&7);
        wp[(c>>1)*516 + (k>>1)*4 + (k&1)*2 + (c&1)] = wh[k*1024 + gc];
    }
    const int un = t >> 3, uu = t & 7;
    float cst = c0[un*256 + wg*8 + uu];

    const int np = t >> 4, cp = t & 15;
    const int n0 = 2*np, n1 = 2*np + 1;
    const int c0l = 2*cp, c1l = 2*cp + 1;
    const int g0 = (c0l>>3)*256 + wg*8 + (c0l&7);
    const int g1 = (c1l>>3)*256 + wg*8 + (c1l&7);

    const float4* hs4 = (const float4*)hs;
    const float4* wp4 = (const float4*)wp;
    __syncthreads();                        // wp ready

    for(int st=0; st<64; ++st){
        const float* gr0 = gx + (size_t)(st*32 + n0)*1024;
        const float* gr1 = gx + (size_t)(st*32 + n1)*1024;
        float gx00 = gr0[g0], gx01 = gr0[g1];
        float gx10 = gr1[g0], gx11 = gr1[g1];

        if(st == 0){
            const float4* hp4 = (const float4*)h0;
            #pragma unroll
            for(int i=0;i<8;i++){
                int q = t + 256*i;
                int row = q >> 6, col4 = q & 63;
                ((float4*)hs)[row*65 + col4] = hp4[q];
            }
        } else {
            const unsigned long long* src = hbuf + (size_t)(st-1)*8192;
            const unsigned tag = (unsigned)st;
            unsigned long long v[32];
            #pragma unroll
            for(int i=0;i<32;i++)
                v[i] = __hip_atomic_load(&src[i*256 + t],
                    __ATOMIC_RELAXED, __HIP_MEMORY_SCOPE_AGENT);
            unsigned spins = 0;
            for(;;){
                bool ok = true;
                #pragma unroll
                for(int i=0;i<32;i++){
                    if((unsigned)(v[i] >> 32) != tag){
                        v[i] = __hip_atomic_load(&src[i*256 + t],
                            __ATOMIC_RELAXED, __HIP_MEMORY_SCOPE_AGENT);
                        ok = false;
                    }
                }
                if(ok) break;
                __builtin_amdgcn_s_sleep(1);
                if(++spins > (1u<<21)) break;       // failsafe: no hard hang
            }
            #pragma unroll
            for(int i=0;i<32;i++)
                hs[i*260 + t] = __uint_as_float((unsigned)v[i]);
        }
        __syncthreads();

        float a00=0.f, a01=0.f, a10=0.f, a11=0.f;
        const float4* h0r = hs4 + n0*65;
        const float4* h1r = hs4 + n1*65;
        const float4* wr  = wp4 + cp*129;
        #pragma unroll 8
        for(int k4=0;k4<64;k4++){
            float4 A = wr[2*k4], B = wr[2*k4+1];
            float4 x = h0r[k4], y = h1r[k4];
            a00 += x.x*A.x + x.y*A.z + x.z*B.x + x.w*B.z;
            a01 += x.x*A.y + x.y*A.w + x.z*B.y + x.w*B.w;
            a10 += y.x*A.x + y.y*A.z + y.z*B.x + y.w*B.z;
            a11 += y.x*A.y + y.y*A.w + y.z*B.y + y.w*B.w;
        }
        gl[n0*33 + c0l] = a00 + gx00;
        gl[n0*33 + c1l] = a01 + gx01;
        gl[n1*33 + c0l] = a10 + gx10;
        gl[n1*33 + c1l] = a11 + gx11;
        __syncthreads();

        {
            float i_ = gl[un*33 +      uu];
            float j_ = gl[un*33 +  8 + uu];
            float f_ = gl[un*33 + 16 + uu];
            float o_ = gl[un*33 + 24 + uu];
            cst = cst*sigmf(f_ + 1.f) + sigmf(i_)*tanhf(j_);
            float h = tanhf(cst)*sigmf(o_);
            int col = wg*8 + uu;
            feats[(un*64 + st)*256 + col] = h;
            unsigned long long pv =
                ((unsigned long long)(unsigned)(st+1) << 32) |
                (unsigned long long)__float_as_uint(h);
            __hip_atomic_store(&hbuf[(size_t)st*8192 + un*256 + col], pv,
                               __ATOMIC_RELAXED, __HIP_MEMORY_SCOPE_AGENT);
        }
        __syncthreads();
    }
}

// ---------------- final FC: logits[p][18] = feats[p] @ fc_w + fc_b ----------
__global__ __launch_bounds__(64) void fc_kernel(
    const float* __restrict__ feats, const float* __restrict__ fw,
    const float* __restrict__ fb,    float* __restrict__ out)
{
    __shared__ float h[256];
    int p = blockIdx.x, t = threadIdx.x;
    *(float4*)&h[t*4] = *(const float4*)(feats + p*256 + t*4);
    __syncthreads();
    if(t < 18){
        float acc = fb[t];
        for(int k=0;k<256;k++) acc += h[k]*fw[k*18 + t];
        out[p*18 + t] = acc;
    }
}

extern "C" void kernel_launch(void* const* d_in, const int* in_sizes, int n_in,
                              void* d_out, int out_size, void* d_ws, size_t ws_size,
                              hipStream_t stream) {
    const float* inp = (const float*)d_in[0];
    const float* w1  = (const float*)d_in[1];  const float* b1 = (const float*)d_in[2];
    const float* w2  = (const float*)d_in[3];  const float* b2 = (const float*)d_in[4];
    const float* w3  = (const float*)d_in[5];  const float* b3 = (const float*)d_in[6];
    const float* w4  = (const float*)d_in[7];  const float* b4 = (const float*)d_in[8];
    const float* lw  = (const float*)d_in[9];  const float* lb = (const float*)d_in[10];
    const float* fw  = (const float*)d_in[11]; const float* fb = (const float*)d_in[12];
    const float* c0  = (const float*)d_in[13]; const float* h0 = (const float*)d_in[14];
    float* out = (float*)d_out;
    float* ws  = (float*)d_ws;

    const size_t n1 = (size_t)32*3612672;   // conv1 out (NHWC, same float count)
    const size_t n3 = (size_t)32*247808;    // conv3 out
    const size_t n4 = (size_t)32*73728;     // conv4 out

    float* p1 = ws;
    float* p2 = p1 + n1;                    // conv2 out (28.9M floats)
    float* p3 = ws;                         // reuse p1 region (conv3 reads only p2)
    float* p4 = p3 + n3;
    float* at = p4 + n4;                    // [1152][2048]
    float* gxb   = at  + (size_t)1152*2048; // [2048][1024]
    float* feats = gxb + (size_t)2048*1024; // [2048][256]
    unsigned long long* hbuf =
        (unsigned long long*)(feats + (size_t)2048*256);  // [64][32][256] u64

    conv1_kernel<<<7056,256,0,stream>>>(inp, w1, b1, p1);
    // conv2: 7 row-tiles x 2048 imgs (OROWS=3 -> 63 px, 37.8 KB LDS, 4 WG/CU)
    convS_kernel<42,42,21,21,0,3,7,1><<<14336,256,0,stream>>>(p1, w2, b2, p2);
    // conv3: whole image (121 px in 2 rounds, 56.5 KB LDS)
    convS_kernel<21,21,11,11,1,11,1,2><<<2048,256,0,stream>>>(p2, w3, b3, p3);
    // conv4: whole image (36 px, 15.5 KB LDS)
    convS_kernel<11,11, 6, 6,1, 6,1,1><<<2048,256,0,stream>>>(p3, w4, b4, p4);
    relayout_kernel<<<9216,256,0,stream>>>(p4, at, hbuf);
    gx_gemm_kernel<<<dim3(64,4),256,0,stream>>>(at, lw, lb, gxb);
    lstm_coop_kernel<<<32,256,0,stream>>>(gxb, lw, c0, h0, feats, hbuf);
    fc_kernel<<<2048,64,0,stream>>>(feats, fw, fb, out);
}

// Round 10
// 2124.439 us; speedup vs baseline: 1.2570x; 1.2570x over previous
//
#include <hip/hip_runtime.h>
#include <math.h>

#define NTRAJ 32
#define TLEN  64
#define BATCH (NTRAJ*TLEN)   // 2048

__device__ __forceinline__ float eluf(float x){ return x > 0.f ? x : expm1f(x); }
__device__ __forceinline__ float sigmf(float x){ return 1.f/(1.f+expf(-x)); }

// ---------------- conv1 (pair): NHWC C=4 -> NHWC [2048][42][42][32] -----------
__global__ __launch_bounds__(256) void conv1_kernel(
    const float* __restrict__ in,   // [2048][84][84][4]
    const float* __restrict__ w,    // [3][3][4][32] HWIO
    const float* __restrict__ b,    // [32]
    float* __restrict__ out)        // [2048][42][42][32]
{
    constexpr int IH=84, IW=84, OH=42, OW=42, PPR=21;   // 21 pairs/row
    int bid = blockIdx.x;
    bid = (bid & 7)*882 + (bid >> 3);            // XCD swizzle (7056/8)
    int pos = bid*256 + threadIdx.x;             // 1,806,336 exactly
    int n   = pos / (OH*PPR);
    int rem = pos % (OH*PPR);
    int oy  = rem / PPR;
    int ox0 = 2*(rem % PPR);                     // OW even -> pair always valid
    float acc0[32], acc1[32];
    #pragma unroll
    for(int o=0;o<32;o++){ acc0[o] = b[o]; acc1[o] = b[o]; }
    const int ix0 = 2*ox0;                       // PB = 0
    for(int ky=0; ky<3; ky++){
        int iy = 2*oy + ky;
        if(iy >= IH) continue;
        const float* rowp = in + ((size_t)(n*IH + iy)*IW)*4;
        float4 xc[5];
        #pragma unroll
        for(int j=0;j<5;j++){
            int ixc = ix0 + j;
            xc[j] = (ixc < IW) ? *(const float4*)(rowp + ixc*4)
                               : make_float4(0.f,0.f,0.f,0.f);
        }
        #pragma unroll
        for(int kx=0;kx<3;kx++){
            const float* wk = w + (ky*3 + kx)*128;
            const float* xa = (const float*)&xc[kx];
            const float* xb = (const float*)&xc[kx+2];
            #pragma unroll
            for(int e=0;e<4;e++){
                float a_ = xa[e], b_ = xb[e];
                const float* wo = wk + e*32;
                #pragma unroll
                for(int o=0;o<32;o++){ acc0[o] += a_*wo[o]; acc1[o] += b_*wo[o]; }
            }
        }
    }
    float4* op = (float4*)(out + ((size_t)(n*OH + oy)*OW + ox0)*32);
    #pragma unroll
    for(int q=0;q<8;q++)
        op[q] = make_float4(eluf(acc0[4*q]), eluf(acc0[4*q+1]),
                            eluf(acc0[4*q+2]), eluf(acc0[4*q+3]));
    #pragma unroll
    for(int q=0;q<8;q++)
        op[8+q] = make_float4(eluf(acc1[4*q]), eluf(acc1[4*q+1]),
                              eluf(acc1[4*q+2]), eluf(acc1[4*q+3]));
}

// ---------------- conv2/3/4 (LDS tile + channel-split passes) -----------------
// r2's proven compute shape (thread = px, acc[32], weights loop-var-uniform ->
// s_load) + LDS-staged input (fixes over-fetch). LDS capacity solved by
// staging NCH=32/CSPLIT input channels per pass; acc[32] persists across
// passes. Odd row pitch (IWP) + odd plane pitch (NPXP) break the stride-2
// even-bank pattern. No threadIdx in any weight address.
template<int IH,int IW,int OH,int OW,int PB,int OROWS,int NTILES,int CSPLIT>
__global__ __launch_bounds__(256) void convL_kernel(
    const float* __restrict__ in,   // [BATCH][IH][IW][32]
    const float* __restrict__ w,    // [3][3][32][32] HWIO
    const float* __restrict__ b,    // [32]
    float* __restrict__ out)        // [BATCH][OH][OW][32]
{
    constexpr int SROWS = (NTILES==1) ? IH : (2*OROWS+1);
    constexpr int IWP   = (IW & 1) ? IW : IW+1;       // odd row pitch
    constexpr int NPXP  = (SROWS*IWP) | 1;            // odd plane pitch
    constexpr int NCH   = 32/CSPLIT;                  // channels per pass
    constexpr int GPP   = NCH/4;                      // f4 groups per pass
    __shared__ float xs[NCH*NPXP];
    int bid = blockIdx.x;
    bid = (bid & 7)*(gridDim.x >> 3) + (bid >> 3);    // XCD swizzle (%8==0)
    const int img  = bid / NTILES;
    const int tile = bid % NTILES;
    const int oy0  = tile*OROWS;
    const int R    = (NTILES==1) ? OH : min(OROWS, OH-oy0);
    const int ys   = (NTILES==1) ? 0 : (2*oy0);       // PB==0 whenever NTILES>1
    const int rows = min(IH - ys, SROWS);
    const int t = threadIdx.x;
    const bool valid = (t < R*OW);
    int oy=0, ox=0;
    if(valid){ oy = oy0 + t/OW; ox = t%OW; }
    float acc[32];
    #pragma unroll
    for(int o=0;o<32;o++) acc[o] = b[o];
    const float4* gs = (const float4*)(in + ((size_t)img*IH + ys)*(size_t)IW*32);
    for(int pass=0; pass<CSPLIT; ++pass){
        // ---- stage NCH channels of the tile (each line fetched once/pass)
        for(int e=t; e<rows*IW*GPP; e+=256){
            int px = e/GPP, g = e%GPP;
            float4 v = gs[px*8 + pass*GPP + g];
            int row = px/IW, col = px%IW;
            int lb = row*IWP + col;
            xs[(g*4+0)*NPXP + lb] = v.x;
            xs[(g*4+1)*NPXP + lb] = v.y;
            xs[(g*4+2)*NPXP + lb] = v.z;
            xs[(g*4+3)*NPXP + lb] = v.w;
        }
        __syncthreads();
        if(valid){
            for(int ky=0;ky<3;ky++){
                int iy = 2*oy + ky - PB;
                if(iy < ys || iy >= IH) continue;     // covers iy<0 too
                for(int kx=0;kx<3;kx++){
                    int ix = 2*ox + kx - PB;
                    if((unsigned)ix >= (unsigned)IW) continue;
                    int base = (iy - ys)*IWP + ix;
                    const float* wt = w + (ky*3+kx)*1024 + pass*NCH*32; // uniform
                    #pragma unroll
                    for(int ci=0;ci<NCH;ci++){
                        float x = xs[ci*NPXP + base];
                        const float* wo = wt + ci*32;                  // uniform
                        #pragma unroll
                        for(int o=0;o<32;o++) acc[o] += x*wo[o];
                    }
                }
            }
        }
        __syncthreads();                              // xs safe to restage
    }
    if(valid){
        float4* op = (float4*)(out + ((size_t)(img*OH+oy)*OW+ox)*32);
        #pragma unroll
        for(int q=0;q<8;q++)
            op[q] = make_float4(eluf(acc[4*q]), eluf(acc[4*q+1]),
                                eluf(acc[4*q+2]), eluf(acc[4*q+3]));
    }
}

// ---------------- conv4 NHWC ([nt][feat]) -> A_T[feat=1152][row=2048] ---------
// Also zeroes the tagged h-exchange buffer every launch (poison/rep safe).
__global__ __launch_bounds__(256) void relayout_kernel(
    const float* __restrict__ p4,   // [2048(nt)][1152(f)]
    float* __restrict__ at,         // [1152][2048], row r = t*32+n
    unsigned long long* __restrict__ hbuf)  // [64][32][256] tagged
{
    int i = blockIdx.x*256 + threadIdx.x;   // 2,359,296 exactly
    if(i < 64*8192) hbuf[i] = 0ull;         // clear tags
    int f = i >> 11, r = i & 2047;          // write coalesced over r
    int tt = r >> 5, n = r & 31;            // r = t*32 + n
    int nt = n*64 + tt;
    at[i] = p4[nt*1152 + f];
}

// ---------------- gate pre-projection: gx[r][1024] = A_T^T @ Wx + b ----------
__global__ __launch_bounds__(256) void gx_gemm_kernel(
    const float* __restrict__ at,   // [1152][2048]
    const float* __restrict__ lw,   // [1408][1024] (rows 0..1151 = Wx)
    const float* __restrict__ lb,   // [1024]
    float* __restrict__ gx)         // [2048][1024], row r = t*32+n
{
    int lane = threadIdx.x & 63;
    int wv   = threadIdx.x >> 6;
    int r0   = blockIdx.x * 32;                    // grid.x = 64
    int oc   = blockIdx.y*256 + wv*64 + lane;      // grid.y = 4
    float acc[32];
    float bias = lb[oc];
    #pragma unroll
    for(int i=0;i<32;i++) acc[i] = bias;
    #pragma unroll 2
    for(int k=0;k<1152;k++){
        float wval = lw[k*1024 + oc];              // coalesced v-load
        const float* ap = at + k*2048 + r0;        // uniform -> s_load_dwordx16
        #pragma unroll
        for(int i=0;i<32;i++) acc[i] += ap[i] * wval;
    }
    #pragma unroll
    for(int i=0;i<32;i++) gx[(r0+i)*1024 + oc] = acc[i];  // coalesced
}

// ---------------- cooperative weight-stationary LSTM, 32 WGs ------------------
// (unchanged: batched tagged u64 exchange, fence-free)
__global__ __launch_bounds__(256) void lstm_coop_kernel(
    const float* __restrict__ gx,   // [2048][1024], row = st*32+n (bias folded)
    const float* __restrict__ lw,   // [1408][1024]; rows 1152.. = Wh
    const float* __restrict__ c0,   // [32][256]
    const float* __restrict__ h0,   // [32][256]
    float* __restrict__ feats,      // [2048][256], row = n*64+st
    unsigned long long* __restrict__ hbuf)  // [64][32][256] tagged, pre-zeroed
{
    __shared__ float hs[32*260];    // h(st-1), row stride 260 (bank-spread)
    __shared__ float wp[16*516];    // Wh pairs, stride 129 f4
    __shared__ float gl[32*33];     // gate buffer

    const int wg = blockIdx.x;      // 0..31
    const int t  = threadIdx.x;
    const float* wh = lw + 1152*1024;

    for(int i=0;i<32;i++){
        int e = t + 256*i;                  // 8192 elements
        int k = e >> 5, c = e & 31;
        int gc = (c>>3)*256 + wg*8 + (c&7);
        wp[(c>>1)*516 + (k>>1)*4 + (k&1)*2 + (c&1)] = wh[k*1024 + gc];
    }
    const int un = t >> 3, uu = t & 7;
    float cst = c0[un*256 + wg*8 + uu];

    const int np = t >> 4, cp = t & 15;
    const int n0 = 2*np, n1 = 2*np + 1;
    const int c0l = 2*cp, c1l = 2*cp + 1;
    const int g0 = (c0l>>3)*256 + wg*8 + (c0l&7);
    const int g1 = (c1l>>3)*256 + wg*8 + (c1l&7);

    const float4* hs4 = (const float4*)hs;
    const float4* wp4 = (const float4*)wp;
    __syncthreads();                        // wp ready

    for(int st=0; st<64; ++st){
        const float* gr0 = gx + (size_t)(st*32 + n0)*1024;
        const float* gr1 = gx + (size_t)(st*32 + n1)*1024;
        float gx00 = gr0[g0], gx01 = gr0[g1];
        float gx10 = gr1[g0], gx11 = gr1[g1];

        if(st == 0){
            const float4* hp4 = (const float4*)h0;
            #pragma unroll
            for(int i=0;i<8;i++){
                int q = t + 256*i;
                int row = q >> 6, col4 = q & 63;
                ((float4*)hs)[row*65 + col4] = hp4[q];
            }
        } else {
            const unsigned long long* src = hbuf + (size_t)(st-1)*8192;
            const unsigned tag = (unsigned)st;
            unsigned long long v[32];
            #pragma unroll
            for(int i=0;i<32;i++)
                v[i] = __hip_atomic_load(&src[i*256 + t],
                    __ATOMIC_RELAXED, __HIP_MEMORY_SCOPE_AGENT);
            unsigned spins = 0;
            for(;;){
                bool ok = true;
                #pragma unroll
                for(int i=0;i<32;i++){
                    if((unsigned)(v[i] >> 32) != tag){
                        v[i] = __hip_atomic_load(&src[i*256 + t],
                            __ATOMIC_RELAXED, __HIP_MEMORY_SCOPE_AGENT);
                        ok = false;
                    }
                }
                if(ok) break;
                __builtin_amdgcn_s_sleep(1);
                if(++spins > (1u<<21)) break;       // failsafe: no hard hang
            }
            #pragma unroll
            for(int i=0;i<32;i++)
                hs[i*260 + t] = __uint_as_float((unsigned)v[i]);
        }
        __syncthreads();

        float a00=0.f, a01=0.f, a10=0.f, a11=0.f;
        const float4* h0r = hs4 + n0*65;
        const float4* h1r = hs4 + n1*65;
        const float4* wr  = wp4 + cp*129;
        #pragma unroll 8
        for(int k4=0;k4<64;k4++){
            float4 A = wr[2*k4], B = wr[2*k4+1];
            float4 x = h0r[k4], y = h1r[k4];
            a00 += x.x*A.x + x.y*A.z + x.z*B.x + x.w*B.z;
            a01 += x.x*A.y + x.y*A.w + x.z*B.y + x.w*B.w;
            a10 += y.x*A.x + y.y*A.z + y.z*B.x + y.w*B.z;
            a11 += y.x*A.y + y.y*A.w + y.z*B.y + y.w*B.w;
        }
        gl[n0*33 + c0l] = a00 + gx00;
        gl[n0*33 + c1l] = a01 + gx01;
        gl[n1*33 + c0l] = a10 + gx10;
        gl[n1*33 + c1l] = a11 + gx11;
        __syncthreads();

        {
            float i_ = gl[un*33 +      uu];
            float j_ = gl[un*33 +  8 + uu];
            float f_ = gl[un*33 + 16 + uu];
            float o_ = gl[un*33 + 24 + uu];
            cst = cst*sigmf(f_ + 1.f) + sigmf(i_)*tanhf(j_);
            float h = tanhf(cst)*sigmf(o_);
            int col = wg*8 + uu;
            feats[(un*64 + st)*256 + col] = h;
            unsigned long long pv =
                ((unsigned long long)(unsigned)(st+1) << 32) |
                (unsigned long long)__float_as_uint(h);
            __hip_atomic_store(&hbuf[(size_t)st*8192 + un*256 + col], pv,
                               __ATOMIC_RELAXED, __HIP_MEMORY_SCOPE_AGENT);
        }
        __syncthreads();
    }
}

// ---------------- final FC: logits[p][18] = feats[p] @ fc_w + fc_b ----------
__global__ __launch_bounds__(64) void fc_kernel(
    const float* __restrict__ feats, const float* __restrict__ fw,
    const float* __restrict__ fb,    float* __restrict__ out)
{
    __shared__ float h[256];
    int p = blockIdx.x, t = threadIdx.x;
    *(float4*)&h[t*4] = *(const float4*)(feats + p*256 + t*4);
    __syncthreads();
    if(t < 18){
        float acc = fb[t];
        for(int k=0;k<256;k++) acc += h[k]*fw[k*18 + t];
        out[p*18 + t] = acc;
    }
}

extern "C" void kernel_launch(void* const* d_in, const int* in_sizes, int n_in,
                              void* d_out, int out_size, void* d_ws, size_t ws_size,
                              hipStream_t stream) {
    const float* inp = (const float*)d_in[0];
    const float* w1  = (const float*)d_in[1];  const float* b1 = (const float*)d_in[2];
    const float* w2  = (const float*)d_in[3];  const float* b2 = (const float*)d_in[4];
    const float* w3  = (const float*)d_in[5];  const float* b3 = (const float*)d_in[6];
    const float* w4  = (const float*)d_in[7];  const float* b4 = (const float*)d_in[8];
    const float* lw  = (const float*)d_in[9];  const float* lb = (const float*)d_in[10];
    const float* fw  = (const float*)d_in[11]; const float* fb = (const float*)d_in[12];
    const float* c0  = (const float*)d_in[13]; const float* h0 = (const float*)d_in[14];
    float* out = (float*)d_out;
    float* ws  = (float*)d_ws;

    const size_t n1 = (size_t)32*3612672;   // conv1 out (NHWC, same float count)
    const size_t n3 = (size_t)32*247808;    // conv3 out
    const size_t n4 = (size_t)32*73728;     // conv4 out

    float* p1 = ws;
    float* p2 = p1 + n1;                    // conv2 out (28.9M floats)
    float* p3 = ws;                         // reuse p1 region (conv3 reads only p2)
    float* p4 = p3 + n3;
    float* at = p4 + n4;                    // [1152][2048]
    float* gxb   = at  + (size_t)1152*2048; // [2048][1024]
    float* feats = gxb + (size_t)2048*1024; // [2048][256]
    unsigned long long* hbuf =
        (unsigned long long*)(feats + (size_t)2048*256);  // [64][32][256] u64

    conv1_kernel<<<7056,256,0,stream>>>(inp, w1, b1, p1);
    // conv2: 2 row-tiles (12+9 rows) x 2048 imgs; 16ch x 2 passes, 68.8KB LDS
    convL_kernel<42,42,21,21,0,12,2,2><<<4096,256,0,stream>>>(p1, w2, b2, p2);
    // conv3: whole image; 16ch x 2 passes, 28.2KB LDS
    convL_kernel<21,21,11,11,1,11,1,2><<<2048,256,0,stream>>>(p2, w3, b3, p3);
    // conv4: whole image; 32ch single pass, 15.5KB LDS
    convL_kernel<11,11, 6, 6,1, 6,1,1><<<2048,256,0,stream>>>(p3, w4, b4, p4);
    relayout_kernel<<<9216,256,0,stream>>>(p4, at, hbuf);
    gx_gemm_kernel<<<dim3(64,4),256,0,stream>>>(at, lw, lb, gxb);
    lstm_coop_kernel<<<32,256,0,stream>>>(gxb, lw, c0, h0, feats, hbuf);
    fc_kernel<<<2048,64,0,stream>>>(feats, fw, fb, out);
}